// Round 1
// baseline (593.810 us; speedup 1.0000x reference)
//
#include <hip/hip_runtime.h>
#include <hip/hip_cooperative_groups.h>

namespace cg = cooperative_groups;

// Problem dims
#define S_DIM 128
#define N_DIM 256
#define H_DIM 1024
#define E_DIM 512
#define V_DIM 32000
#define KE_DIM 1024
#define CIN 2560   // H + E + H  (A2 = [ctx | emb_x | h0])

typedef unsigned short u16;
typedef __bf16 bf16x8 __attribute__((ext_vector_type(8)));
typedef float  f32x4  __attribute__((ext_vector_type(4)));

union U16x8 { uint4 u; bf16x8 b; };

// f32 -> bf16 RNE
__device__ __forceinline__ unsigned f2bf(float x) {
  unsigned u = __float_as_uint(x);
  return (u + 0x7FFFu + ((u >> 16) & 1u)) >> 16;
}
__device__ __forceinline__ unsigned pk2(float a, float b) {
  return f2bf(a) | (f2bf(b) << 16);
}

__device__ __forceinline__ bf16x8 frag_from_global(const u16* p) {
  U16x8 t; t.u = *(const uint4*)p; return t.b;
}
__device__ __forceinline__ bf16x8 frag_from_lds(const u16* base, int byteoff) {
  U16x8 t; t.u = *(const uint4*)((const char*)base + byteoff); return t.b;
}

// XOR-swizzled LDS addressing: 16B chunks, chunk' = chunk ^ (row&7).
__device__ __forceinline__ int loff64(int row, int k) {   // 64-col tile (128 B/row)
  return row * 128 + ((((k >> 3) ^ (row & 7)) << 4) | ((k & 7) << 1));
}
__device__ __forceinline__ int loff128(int row, int k) {  // 128-col tile (256 B/row)
  return row * 256 + ((((k >> 3) ^ (row & 7)) << 4) | ((k & 7) << 1));
}

__device__ __forceinline__ f32x4 mfma16(bf16x8 a, bf16x8 b, f32x4 c) {
  return __builtin_amdgcn_mfma_f32_16x16x32_bf16(a, b, c, 0, 0, 0);
}

// Phase-overlaid LDS (union): max 32.9 KB
struct ShP1 { float acc[8][H_DIM]; float ml[16]; };           // 32832 B
struct ShP2 { u16 b[16 * 128]; float sg[256][17]; };          // 21504 B (sg padded: stride 17)
struct ShP3 { u16 b[64 * 64]; };                              //  8192 B
union ShAll { ShP1 p1; ShP2 p2; ShP3 p3; };

// ---------------------------------------------------------------------------
// ONE persistent cooperative kernel. grid = 256 blocks x 512 threads
// (1 block/CU, 8 waves = 2/SIMD). Two grid.sync()s replace three kernel
// launch boundaries; LSTM pointwise fused into gates-GEMM epilogue
// (gates buffer + k2b launch eliminated).
// ---------------------------------------------------------------------------
__global__ __launch_bounds__(512) void kmega(
    const int*   __restrict__ inp,  const float* __restrict__ enc,
    const float* __restrict__ hid,  const float* __restrict__ cell0,
    const float* __restrict__ emb,  const float* __restrict__ Wen,
    const float* __restrict__ ben,  const float* __restrict__ Wih,
    const float* __restrict__ bih,  const float* __restrict__ Whh,
    const float* __restrict__ bhh,  const float* __restrict__ Wfc,
    const float* __restrict__ bfc,
    u16* __restrict__ A2, u16* __restrict__ h1b,
    float* __restrict__ pred, float* __restrict__ h1, float* __restrict__ c1)
{
  __shared__ ShAll sh;
  cg::grid_group grid = cg::this_grid();
  const int t    = threadIdx.x;
  const int wave = t >> 6, lane = t & 63;
  const int quad = lane >> 4, l15 = lane & 15;

  // ========== Phase 1: per-n online-softmax attention, builds A2 ==========
  // block n streams enc[:, n, :] once (134 MB grid-wide). 8 waves own
  // s = wave, wave+8, ...  (was 4 waves -> 2x latency hiding).
  {
    const int n = blockIdx.x;
    const float* Wrow = Wen + (KE_DIM - 1) * (2 * H_DIM);
    float4 we[4];
    #pragma unroll
    for (int ks = 0; ks < 4; ++ks)
      we[ks] = *(const float4*)(Wrow + H_DIM + ks * 256 + lane * 4);

    // hidden-part dot (s-invariant), redundant per wave
    float hd = 0.f;
    #pragma unroll
    for (int ks = 0; ks < 4; ++ks) {
      float4 wh = *(const float4*)(Wrow + ks * 256 + lane * 4);
      float4 hv = *(const float4*)(hid + n * H_DIM + ks * 256 + lane * 4);
      hd += wh.x * hv.x + wh.y * hv.y + wh.z * hv.z + wh.w * hv.w;
    }
    #pragma unroll
    for (int off = 32; off > 0; off >>= 1) hd += __shfl_xor(hd, off, 64);
    const float ebase = hd + ben[KE_DIM - 1];

    float m = -INFINITY, l = 0.f;
    float4 acc[4];
    #pragma unroll
    for (int ks = 0; ks < 4; ++ks) acc[ks] = make_float4(0.f, 0.f, 0.f, 0.f);

    const long rstride = 8L * N_DIM * H_DIM;
    const float* p = enc + ((long)wave * N_DIM + n) * H_DIM + lane * 4;
    float4 cur[4];
    #pragma unroll
    for (int ks = 0; ks < 4; ++ks) cur[ks] = *(const float4*)(p + ks * 256);

    for (int s = wave; s < S_DIM; s += 8) {
      float4 nxt[4];
      const float* pn = p + rstride;
      const bool has = (s + 8 < S_DIM);
      if (has) {
        #pragma unroll
        for (int ks = 0; ks < 4; ++ks) nxt[ks] = *(const float4*)(pn + ks * 256);
      }
      float d = 0.f;
      #pragma unroll
      for (int ks = 0; ks < 4; ++ks)
        d += we[ks].x * cur[ks].x + we[ks].y * cur[ks].y +
             we[ks].z * cur[ks].z + we[ks].w * cur[ks].w;
      #pragma unroll
      for (int off = 32; off > 0; off >>= 1) d += __shfl_xor(d, off, 64);
      const float e  = fmaxf(ebase + d, 0.f);
      const float nm = fmaxf(m, e);
      const float sc = __expf(m - nm);
      const float pe = __expf(e - nm);
      l = l * sc + pe;
      #pragma unroll
      for (int ks = 0; ks < 4; ++ks) {
        acc[ks].x = acc[ks].x * sc + pe * cur[ks].x;
        acc[ks].y = acc[ks].y * sc + pe * cur[ks].y;
        acc[ks].z = acc[ks].z * sc + pe * cur[ks].z;
        acc[ks].w = acc[ks].w * sc + pe * cur[ks].w;
      }
      m = nm;
      if (has) {
        #pragma unroll
        for (int ks = 0; ks < 4; ++ks) cur[ks] = nxt[ks];
      }
      p = pn;
    }

    // merge the 8 per-wave online-softmax states
    #pragma unroll
    for (int ks = 0; ks < 4; ++ks)
      *(float4*)&sh.p1.acc[wave][ks * 256 + lane * 4] = acc[ks];
    if (lane == 0) { sh.p1.ml[wave] = m; sh.p1.ml[8 + wave] = l; }
    __syncthreads();

    float M = sh.p1.ml[0];
    #pragma unroll
    for (int w = 1; w < 8; ++w) M = fmaxf(M, sh.p1.ml[w]);
    float f[8]; float L = 0.f;
    #pragma unroll
    for (int w = 0; w < 8; ++w) { f[w] = __expf(sh.p1.ml[w] - M); L += sh.p1.ml[8 + w] * f[w]; }
    const float invL = 1.0f / L;
    {
      const int e0 = t * 2;   // 512 threads x 2 elems = 1024 ctx cols
      float v0 = 0.f, v1 = 0.f;
      #pragma unroll
      for (int w = 0; w < 8; ++w) {
        v0 += sh.p1.acc[w][e0]     * f[w];
        v1 += sh.p1.acc[w][e0 + 1] * f[w];
      }
      *(unsigned*)&A2[(long)n * CIN + e0] = pk2(v0 * invL, v1 * invL);
    }
    // A2 tail: emb gather (cols 1024..1535) then h0 copy (cols 1536..2559)
    const int idx = inp[n];
    for (int j = t; j < E_DIM + H_DIM; j += 512) {
      float v = (j < E_DIM) ? emb[(long)idx * E_DIM + j]
                            : hid[n * H_DIM + (j - E_DIM)];
      A2[(long)n * CIN + H_DIM + j] = (u16)f2bf(v);
    }
  }
  __threadfence();
  grid.sync();

  // ========== Phase 2: gates GEMM + fused LSTM pointwise ==========
  // Block b owns h = 4b..4b+3; its 16 B-rows are j = g*1024 + 4b + q
  // (4 gates x 4 h) so all four gate values for each (n,h) land in this
  // block -> LSTM applied in epilogue, gates buffer never materialized.
  {
    const int b  = blockIdx.x;
    const int br = t >> 5;          // 0..15  (B row within tile)
    const int bk = (t & 31) * 4;    // 0..124 (k offset within tile)
    const int jbr = (br >> 2) * H_DIM + b * 4 + (br & 3);

    f32x4 acc[2];
    acc[0] = (f32x4){0.f, 0.f, 0.f, 0.f};
    acc[1] = (f32x4){0.f, 0.f, 0.f, 0.f};

    // unified B row j = [W_ih[j,0:1536] | W_hh[j,0:1024]]; 1536 = 12*128
    float4 v = *(const float4*)(Wih + (long)jbr * 1536 + bk);

    for (int kt = 0; kt < 20; ++kt) {
      const int k0 = kt * 128;
      uint2 pk; pk.x = pk2(v.x, v.y); pk.y = pk2(v.z, v.w);
      *(uint2*)((char*)sh.p2.b + loff128(br, bk)) = pk;
      if (kt + 1 < 20) {            // register prefetch of next B tile
        const int kn = k0 + 128 + bk;
        const float* sn = (kn < 1536) ? (Wih + (long)jbr * 1536 + kn)
                                      : (Whh + (long)jbr * H_DIM + (kn - 1536));
        v = *(const float4*)sn;
      }
      __syncthreads();
      #pragma unroll
      for (int kstep = 0; kstep < 4; ++kstep) {
        const int kl = kstep * 32 + quad * 8;
        const bf16x8 bfrag = frag_from_lds(sh.p2.b, loff128(l15, kl));
        #pragma unroll
        for (int mt = 0; mt < 2; ++mt) {
          const int row = wave * 32 + mt * 16 + l15;
          const bf16x8 afrag = frag_from_global(A2 + (long)row * CIN + k0 + kl);
          acc[mt] = mfma16(afrag, bfrag, acc[mt]);
        }
      }
      __syncthreads();
    }

    // stage gates into padded LDS, then LSTM pointwise
    {
      const int jj = (l15 >> 2) * H_DIM + b * 4 + (l15 & 3);
      const float bias = bih[jj] + bhh[jj];
      #pragma unroll
      for (int mt = 0; mt < 2; ++mt)
        #pragma unroll
        for (int r = 0; r < 4; ++r)
          sh.p2.sg[wave * 32 + mt * 16 + quad * 4 + r][l15] = acc[mt][r] + bias;
    }
    __syncthreads();
    #pragma unroll
    for (int u = 0; u < 2; ++u) {
      const int id = t + u * 512;         // 1024 (n,q) pairs
      const int n = id >> 2, q = id & 3, h = b * 4 + q;
      const float gi = sh.p2.sg[n][q],      gf = sh.p2.sg[n][4 + q];
      const float gg = sh.p2.sg[n][8 + q],  go = sh.p2.sg[n][12 + q];
      const float si = 1.f / (1.f + __expf(-gi));
      const float sf = 1.f / (1.f + __expf(-gf));
      const float so = 1.f / (1.f + __expf(-go));
      const float tg = tanhf(gg);
      const float cv = sf * cell0[(long)n * H_DIM + h] + si * tg;
      const float hv = so * tanhf(cv);
      c1 [(long)n * H_DIM + h] = cv;
      h1 [(long)n * H_DIM + h] = hv;
      h1b[(long)n * H_DIM + h] = (u16)f2bf(hv);
    }
  }
  __threadfence();
  grid.sync();

  // ========== Phase 3: predictions = h1 @ W_fc^T + b_fc ==========
  // 500 col-tiles of 64 over 256 persistent blocks (blocks 0..243 take 2).
  for (int tile = blockIdx.x; tile < V_DIM / 64; tile += 256) {
    const int j0 = tile * 64;
    const int br = t >> 3;        // 0..63
    const int bk = (t & 7) * 8;   // 0,8,..,56
    const float* bsrc = Wfc + (long)(j0 + br) * H_DIM + bk;

    f32x4 acc[2][4];
    #pragma unroll
    for (int mt = 0; mt < 2; ++mt)
      #pragma unroll
      for (int nt = 0; nt < 4; ++nt) acc[mt][nt] = (f32x4){0.f, 0.f, 0.f, 0.f};

    float4 v0 = *(const float4*)(bsrc);
    float4 v1 = *(const float4*)(bsrc + 4);

    for (int kt = 0; kt < 16; ++kt) {
      const int k0 = kt * 64;
      uint4 pa;
      pa.x = pk2(v0.x, v0.y); pa.y = pk2(v0.z, v0.w);
      pa.z = pk2(v1.x, v1.y); pa.w = pk2(v1.z, v1.w);
      *(uint4*)((char*)sh.p3.b + loff64(br, bk)) = pa;
      if (kt + 1 < 16) {          // register prefetch of next W_fc tile
        const float* sn = bsrc + (k0 + 64);
        v0 = *(const float4*)(sn);
        v1 = *(const float4*)(sn + 4);
      }
      __syncthreads();
      #pragma unroll
      for (int kstep = 0; kstep < 2; ++kstep) {
        const int kl = kstep * 32 + quad * 8;
        bf16x8 bfrag[4], afrag[2];
        #pragma unroll
        for (int nt = 0; nt < 4; ++nt)
          bfrag[nt] = frag_from_lds(sh.p3.b, loff64(nt * 16 + l15, kl));
        #pragma unroll
        for (int mt = 0; mt < 2; ++mt)
          afrag[mt] = frag_from_global(h1b + (long)(wave * 32 + mt * 16 + l15) * H_DIM + k0 + kl);
        #pragma unroll
        for (int mt = 0; mt < 2; ++mt)
          #pragma unroll
          for (int nt = 0; nt < 4; ++nt)
            acc[mt][nt] = mfma16(afrag[mt], bfrag[nt], acc[mt][nt]);
      }
      __syncthreads();
    }

    #pragma unroll
    for (int nt = 0; nt < 4; ++nt) {
      const float bv = bfc[j0 + nt * 16 + l15];
      #pragma unroll
      for (int mt = 0; mt < 2; ++mt) {
        #pragma unroll
        for (int r = 0; r < 4; ++r) {
          const int row = wave * 32 + mt * 16 + quad * 4 + r;
          pred[(long)row * V_DIM + j0 + nt * 16 + l15] = acc[mt][nt][r] + bv;
        }
      }
    }
  }
}

// ---------------------------------------------------------------------------
extern "C" void kernel_launch(void* const* d_in, const int* in_sizes, int n_in,
                              void* d_out, int out_size, void* d_ws, size_t ws_size,
                              hipStream_t stream) {
  const int*   inp  = (const int*)  d_in[0];
  const float* enc  = (const float*)d_in[1];
  const float* hid  = (const float*)d_in[2];
  const float* cel  = (const float*)d_in[3];
  const float* emb  = (const float*)d_in[4];
  const float* Wen  = (const float*)d_in[5];
  const float* ben  = (const float*)d_in[6];
  const float* Wih  = (const float*)d_in[7];
  const float* bih  = (const float*)d_in[8];
  const float* Whh  = (const float*)d_in[9];
  const float* bhh  = (const float*)d_in[10];
  const float* Wfc  = (const float*)d_in[11];
  const float* bfc  = (const float*)d_in[12];

  float* out  = (float*)d_out;
  float* pred = out;                              // [256, 32000]
  float* h1   = out + (long)N_DIM * V_DIM;        // [1, 256, 1024]
  float* c1   = h1 + (long)N_DIM * H_DIM;         // [1, 256, 1024]

  char* ws = (char*)d_ws;
  u16* A2  = (u16*)ws;                            // 256*2560*2 = 1,310,720 B
  u16* h1b = (u16*)(ws + 1310720);                // 256*1024*2 =   524,288 B

  void* args[] = {
    (void*)&inp, (void*)&enc, (void*)&hid, (void*)&cel, (void*)&emb,
    (void*)&Wen, (void*)&ben, (void*)&Wih, (void*)&bih, (void*)&Whh,
    (void*)&bhh, (void*)&Wfc, (void*)&bfc,
    (void*)&A2, (void*)&h1b, (void*)&pred, (void*)&h1, (void*)&c1
  };
  hipLaunchCooperativeKernel((void*)kmega, dim3(N_DIM), dim3(512), args, 0, stream);
}

// Round 2
// 422.843 us; speedup vs baseline: 1.4043x; 1.4043x over previous
//
#include <hip/hip_runtime.h>

// Problem dims
#define S_DIM 128
#define N_DIM 256
#define H_DIM 1024
#define E_DIM 512
#define V_DIM 32000
#define KE_DIM 1024
#define CIN 2560   // H + E + H  (A2 = [ctx | emb_x | h0])

typedef unsigned short u16;
typedef __bf16 bf16x8 __attribute__((ext_vector_type(8)));
typedef float  f32x4  __attribute__((ext_vector_type(4)));

union U16x8 { uint4 u; bf16x8 b; };

// f32 -> bf16 RNE
__device__ __forceinline__ unsigned f2bf(float x) {
  unsigned u = __float_as_uint(x);
  return (u + 0x7FFFu + ((u >> 16) & 1u)) >> 16;
}
__device__ __forceinline__ unsigned pk2(float a, float b) {
  return f2bf(a) | (f2bf(b) << 16);
}

__device__ __forceinline__ bf16x8 frag_from_global(const u16* p) {
  U16x8 t; t.u = *(const uint4*)p; return t.b;
}
__device__ __forceinline__ bf16x8 frag_from_lds(const u16* base, int byteoff) {
  U16x8 t; t.u = *(const uint4*)((const char*)base + byteoff); return t.b;
}

// XOR-swizzled LDS addressing: 16B chunks, chunk' = chunk ^ (row&7).
__device__ __forceinline__ int loff128(int row, int k) {  // 128-col tile (256 B/row)
  return row * 256 + ((((k >> 3) ^ (row & 7)) << 4) | ((k & 7) << 1));
}

__device__ __forceinline__ f32x4 mfma16(bf16x8 a, bf16x8 b, f32x4 c) {
  return __builtin_amdgcn_mfma_f32_16x16x32_bf16(a, b, c, 0, 0, 0);
}

// ---------------------------------------------------------------------------
// Kernel 1: per-n online-softmax attention over s, ctx = sum_s a[s]*enc[s,n,:]
// 512 threads = 8 waves (2/SIMD): 2x latency hiding vs the 4-wave version.
// Epilogue assembles A2 = [bf16(ctx) | bf16(emb[input[n]]) | bf16(h0[n])].
// ---------------------------------------------------------------------------
__global__ __launch_bounds__(512) void k1_attn(
    const float* __restrict__ enc, const float* __restrict__ hid,
    const float* __restrict__ Wen, const float* __restrict__ ben,
    const int* __restrict__ inp, const float* __restrict__ emb,
    u16* __restrict__ A2)
{
  __shared__ float s_acc[8][H_DIM];   // 32 KB
  __shared__ float s_ml[16];
  const int n = blockIdx.x;
  const int t = threadIdx.x;
  const int wave = t >> 6, lane = t & 63;

  // W_energy row K-1: [0:H) multiplies hidden, [H:2H) multiplies encoder
  const float* Wrow = Wen + (KE_DIM - 1) * (2 * H_DIM);
  float4 we[4];
  #pragma unroll
  for (int ks = 0; ks < 4; ++ks)
    we[ks] = *(const float4*)(Wrow + H_DIM + ks * 256 + lane * 4);

  // hidden-part dot (s-invariant), computed redundantly per wave
  float hd = 0.f;
  #pragma unroll
  for (int ks = 0; ks < 4; ++ks) {
    float4 wh = *(const float4*)(Wrow + ks * 256 + lane * 4);
    float4 hv = *(const float4*)(hid + n * H_DIM + ks * 256 + lane * 4);
    hd += wh.x * hv.x + wh.y * hv.y + wh.z * hv.z + wh.w * hv.w;
  }
  #pragma unroll
  for (int off = 32; off > 0; off >>= 1) hd += __shfl_xor(hd, off, 64);
  const float ebase = hd + ben[KE_DIM - 1];

  // online softmax state (per wave; waves own s = wave, wave+8, ...)
  float m = -INFINITY, l = 0.f;
  float4 acc[4];
  #pragma unroll
  for (int ks = 0; ks < 4; ++ks) acc[ks] = make_float4(0.f, 0.f, 0.f, 0.f);

  const long rstride = 8L * N_DIM * H_DIM;
  const float* p = enc + ((long)wave * N_DIM + n) * H_DIM + lane * 4;
  float4 cur[4];
  #pragma unroll
  for (int ks = 0; ks < 4; ++ks) cur[ks] = *(const float4*)(p + ks * 256);

  for (int s = wave; s < S_DIM; s += 8) {
    float4 nxt[4];
    const float* pn = p + rstride;
    const bool has = (s + 8 < S_DIM);
    if (has) {   // prefetch next row to hide HBM latency
      #pragma unroll
      for (int ks = 0; ks < 4; ++ks) nxt[ks] = *(const float4*)(pn + ks * 256);
    }
    float d = 0.f;
    #pragma unroll
    for (int ks = 0; ks < 4; ++ks)
      d += we[ks].x * cur[ks].x + we[ks].y * cur[ks].y +
           we[ks].z * cur[ks].z + we[ks].w * cur[ks].w;
    #pragma unroll
    for (int off = 32; off > 0; off >>= 1) d += __shfl_xor(d, off, 64);
    const float e  = fmaxf(ebase + d, 0.f);          // ReLU
    const float nm = fmaxf(m, e);
    const float sc = __expf(m - nm);                 // 0 on first iter (m=-inf)
    const float pe = __expf(e - nm);
    l = l * sc + pe;
    #pragma unroll
    for (int ks = 0; ks < 4; ++ks) {
      acc[ks].x = acc[ks].x * sc + pe * cur[ks].x;
      acc[ks].y = acc[ks].y * sc + pe * cur[ks].y;
      acc[ks].z = acc[ks].z * sc + pe * cur[ks].z;
      acc[ks].w = acc[ks].w * sc + pe * cur[ks].w;
    }
    m = nm;
    if (has) {
      #pragma unroll
      for (int ks = 0; ks < 4; ++ks) cur[ks] = nxt[ks];
    }
    p = pn;
  }

  // merge the 8 per-wave online-softmax states
  #pragma unroll
  for (int ks = 0; ks < 4; ++ks)
    *(float4*)&s_acc[wave][ks * 256 + lane * 4] = acc[ks];
  if (lane == 0) { s_ml[wave] = m; s_ml[8 + wave] = l; }
  __syncthreads();

  float M = s_ml[0];
  #pragma unroll
  for (int w = 1; w < 8; ++w) M = fmaxf(M, s_ml[w]);
  float f[8]; float L = 0.f;
  #pragma unroll
  for (int w = 0; w < 8; ++w) { f[w] = __expf(s_ml[w] - M); L += s_ml[8 + w] * f[w]; }
  const float invL = 1.0f / L;
  {
    const int e0 = t * 2;   // 512 threads x 2 elems = 1024 ctx cols
    float v0 = 0.f, v1 = 0.f;
    #pragma unroll
    for (int w = 0; w < 8; ++w) {
      v0 += s_acc[w][e0]     * f[w];
      v1 += s_acc[w][e0 + 1] * f[w];
    }
    *(unsigned*)&A2[(long)n * CIN + e0] = pk2(v0 * invL, v1 * invL);
  }

  // A2 tail: emb gather (cols 1024..1535) then h0 copy (cols 1536..2559)
  const int idx = inp[n];
  for (int j = t; j < E_DIM + H_DIM; j += 512) {
    float v = (j < E_DIM) ? emb[(long)idx * E_DIM + j]
                          : hid[n * H_DIM + (j - E_DIM)];
    A2[(long)n * CIN + H_DIM + j] = (u16)f2bf(v);
  }
}

// ---------------------------------------------------------------------------
// Kernel 2: gates GEMM + FUSED LSTM pointwise.  M=256, K=2560, grid=256.
// Gate-interleaved BN=16: block b owns h = 4b..4b+3; its 16 B-rows are
// j = g*1024 + 4b + q (4 gates x 4 h), so all four gate values for each
// (n,h) land in this block -> LSTM applied in epilogue; gates buffer and
// the separate pointwise kernel are eliminated.
// ---------------------------------------------------------------------------
__global__ __launch_bounds__(256) void k2_gates(
    const u16* __restrict__ A2, const float* __restrict__ Wih,
    const float* __restrict__ bih, const float* __restrict__ Whh,
    const float* __restrict__ bhh, const float* __restrict__ cell0,
    float* __restrict__ h1, float* __restrict__ c1, u16* __restrict__ h1b)
{
  __shared__ u16 Blds[16 * 128];     // 4 KB
  __shared__ float sg[256][17];      // 17.4 KB (pad 17: conflict-free)
  const int t = threadIdx.x;
  const int wave = t >> 6, lane = t & 63;
  const int quad = lane >> 4, l15 = lane & 15;
  const int b = blockIdx.x;
  const int br = t >> 4;             // 0..15  (B row within tile)
  const int bk = (t & 15) * 8;       // 0..120 (k offset within tile)
  // gate-interleaved source row for staging row br
  const int jbr = (br >> 2) * H_DIM + b * 4 + (br & 3);

  f32x4 acc[4];
  #pragma unroll
  for (int mt = 0; mt < 4; ++mt) acc[mt] = (f32x4){0.f, 0.f, 0.f, 0.f};

  // unified B row j = [W_ih[j,0:1536] | W_hh[j,0:1024]]; 1536 = 12*128
  const float* s0 = Wih + (long)jbr * 1536 + bk;
  float4 v0 = *(const float4*)s0;
  float4 v1 = *(const float4*)(s0 + 4);

  for (int kt = 0; kt < 20; ++kt) {
    const int k0 = kt * 128;
    uint4 pk;
    pk.x = pk2(v0.x, v0.y); pk.y = pk2(v0.z, v0.w);
    pk.z = pk2(v1.x, v1.y); pk.w = pk2(v1.z, v1.w);
    *(uint4*)((char*)Blds + loff128(br, bk)) = pk;
    if (kt + 1 < 20) {               // register prefetch of next B tile
      const int kn = k0 + 128 + bk;
      const float* sn = (kn < 1536) ? (Wih + (long)jbr * 1536 + kn)
                                    : (Whh + (long)jbr * H_DIM + (kn - 1536));
      v0 = *(const float4*)sn;
      v1 = *(const float4*)(sn + 4);
    }
    __syncthreads();
    #pragma unroll
    for (int kstep = 0; kstep < 4; ++kstep) {
      const int kl = kstep * 32 + quad * 8;
      const bf16x8 bfrag = frag_from_lds(Blds, loff128(l15, kl));
      #pragma unroll
      for (int mt = 0; mt < 4; ++mt) {
        const int row = wave * 64 + mt * 16 + l15;
        const bf16x8 afrag = frag_from_global(A2 + (long)row * CIN + k0 + kl);
        acc[mt] = mfma16(afrag, bfrag, acc[mt]);
      }
    }
    __syncthreads();
  }

  // stage biased gates into padded LDS
  {
    const int jj = (l15 >> 2) * H_DIM + b * 4 + (l15 & 3);
    const float bias = bih[jj] + bhh[jj];
    #pragma unroll
    for (int mt = 0; mt < 4; ++mt)
      #pragma unroll
      for (int r = 0; r < 4; ++r)
        sg[wave * 64 + mt * 16 + quad * 4 + r][l15] = acc[mt][r] + bias;
  }
  __syncthreads();

  // fused LSTM pointwise (PyTorch gate order i,f,g,o)
  #pragma unroll
  for (int u = 0; u < 4; ++u) {
    const int id = t + u * 256;        // 1024 (n,q) pairs
    const int n = id >> 2, q = id & 3, h = b * 4 + q;
    const float gi = sg[n][q],      gf = sg[n][4 + q];
    const float gg = sg[n][8 + q],  go = sg[n][12 + q];
    const float si = 1.f / (1.f + __expf(-gi));
    const float sf = 1.f / (1.f + __expf(-gf));
    const float so = 1.f / (1.f + __expf(-go));
    const float tg = tanhf(gg);
    const float cv = sf * cell0[(long)n * H_DIM + h] + si * tg;
    const float hv = so * tanhf(cv);
    c1 [(long)n * H_DIM + h] = cv;
    h1 [(long)n * H_DIM + h] = hv;
    h1b[(long)n * H_DIM + h] = (u16)f2bf(hv);
  }
}

// ---------------------------------------------------------------------------
// Kernel 3: predictions = h1 @ W_fc^T + b_fc.   M=256, N=32000, K=1024.
// BM=256 (full M: W_fc's 131 MB read exactly once), BN=64, BK=128, grid=500.
// BK=128: half the barriers of BK=64, 8 float4 loads in flight per thread.
// ---------------------------------------------------------------------------
__global__ __launch_bounds__(256) void k3_fc(
    const u16* __restrict__ h1b, const float* __restrict__ Wfc,
    const float* __restrict__ bfc, float* __restrict__ out)
{
  __shared__ u16 Blds[64 * 128];     // 16 KB
  const int t = threadIdx.x;
  const int wave = t >> 6, lane = t & 63;
  const int quad = lane >> 4, l15 = lane & 15;
  const int j0 = blockIdx.x * 64;
  const int br = t >> 2;             // 0..63 (B row within tile)
  const int bk = (t & 3) * 32;       // 0,32,64,96 (k offset within tile)
  const float* bsrc = Wfc + (long)(j0 + br) * H_DIM + bk;

  f32x4 acc[4][4];
  #pragma unroll
  for (int mt = 0; mt < 4; ++mt)
    #pragma unroll
    for (int nt = 0; nt < 4; ++nt) acc[mt][nt] = (f32x4){0.f, 0.f, 0.f, 0.f};

  float4 v[8];
  #pragma unroll
  for (int i = 0; i < 8; ++i) v[i] = *(const float4*)(bsrc + 4 * i);

  for (int kt = 0; kt < 8; ++kt) {
    const int k0 = kt * 128;
    #pragma unroll
    for (int i = 0; i < 4; ++i) {
      uint4 pk;
      pk.x = pk2(v[2*i].x, v[2*i].y); pk.y = pk2(v[2*i].z, v[2*i].w);
      pk.z = pk2(v[2*i+1].x, v[2*i+1].y); pk.w = pk2(v[2*i+1].z, v[2*i+1].w);
      *(uint4*)((char*)Blds + loff128(br, bk + 8 * i)) = pk;
    }
    if (kt + 1 < 8) {                // register prefetch of next W_fc tile
      const float* sn = bsrc + (k0 + 128);
      #pragma unroll
      for (int i = 0; i < 8; ++i) v[i] = *(const float4*)(sn + 4 * i);
    }
    __syncthreads();
    #pragma unroll
    for (int kstep = 0; kstep < 4; ++kstep) {
      const int kl = kstep * 32 + quad * 8;
      bf16x8 bfrag[4], afrag[4];
      #pragma unroll
      for (int nt = 0; nt < 4; ++nt)
        bfrag[nt] = frag_from_lds(Blds, loff128(nt * 16 + l15, kl));
      #pragma unroll
      for (int mt = 0; mt < 4; ++mt)
        afrag[mt] = frag_from_global(h1b + (long)(wave * 64 + mt * 16 + l15) * H_DIM + k0 + kl);
      #pragma unroll
      for (int mt = 0; mt < 4; ++mt)
        #pragma unroll
        for (int nt = 0; nt < 4; ++nt)
          acc[mt][nt] = mfma16(afrag[mt], bfrag[nt], acc[mt][nt]);
    }
    __syncthreads();
  }

  #pragma unroll
  for (int nt = 0; nt < 4; ++nt) {
    const float bv = bfc[j0 + nt * 16 + l15];
    #pragma unroll
    for (int mt = 0; mt < 4; ++mt) {
      #pragma unroll
      for (int r = 0; r < 4; ++r) {
        const int row = wave * 64 + mt * 16 + quad * 4 + r;
        out[(long)row * V_DIM + j0 + nt * 16 + l15] = acc[mt][nt][r] + bv;
      }
    }
  }
}

// ---------------------------------------------------------------------------
extern "C" void kernel_launch(void* const* d_in, const int* in_sizes, int n_in,
                              void* d_out, int out_size, void* d_ws, size_t ws_size,
                              hipStream_t stream) {
  const int*   inp  = (const int*)  d_in[0];
  const float* enc  = (const float*)d_in[1];
  const float* hid  = (const float*)d_in[2];
  const float* cel  = (const float*)d_in[3];
  const float* emb  = (const float*)d_in[4];
  const float* Wen  = (const float*)d_in[5];
  const float* ben  = (const float*)d_in[6];
  const float* Wih  = (const float*)d_in[7];
  const float* bih  = (const float*)d_in[8];
  const float* Whh  = (const float*)d_in[9];
  const float* bhh  = (const float*)d_in[10];
  const float* Wfc  = (const float*)d_in[11];
  const float* bfc  = (const float*)d_in[12];

  float* out  = (float*)d_out;
  float* pred = out;                              // [256, 32000]
  float* h1   = out + (long)N_DIM * V_DIM;        // [1, 256, 1024]
  float* c1   = h1 + (long)N_DIM * H_DIM;         // [1, 256, 1024]

  char* ws = (char*)d_ws;
  u16* A2  = (u16*)ws;                            // 256*2560*2 = 1,310,720 B
  u16* h1b = (u16*)(ws + 1310720);                // 256*1024*2 =   524,288 B

  k1_attn <<<N_DIM,    512, 0, stream>>>(enc, hid, Wen, ben, inp, emb, A2);
  k2_gates<<<N_DIM,    256, 0, stream>>>(A2, Wih, bih, Whh, bhh, cel, h1, c1, h1b);
  k3_fc   <<<V_DIM/64, 256, 0, stream>>>(h1b, Wfc, bfc, pred);
}